// Round 5
// baseline (160.957 us; speedup 1.0000x reference)
//
#include <hip/hip_runtime.h>
#include <hip/hip_bf16.h>

// GAT layer, MI355X. B=32, N=512, Fin=256, F=64, H=8. fp32 in / fp32 out
// (probe-confirmed R3/R4). Fused kernel, one block per (b, h, i-half).
// R5: LDS 107->75.5 KB (W staged in k=32 panels) and grid 256->512 blocks
// so 2 blocks/CU are co-resident (R4 was 1 block/CU, latency-bound:
// occ 19%, hbm 40%, VALU 36%). Each block computes the full 512x64 h-tile
// (duplicate x@W across the two i-halves: +4.3 GFLOP total, ~2 us) and
// runs attention for its 256 i-rows. Softmax normalization commuted past
// PV: out_i = sum_j p_ij h_j / sum_j p_ij, p = exp(lrelu(e)) * mask.

#define ALPHA 0.2f

typedef __bf16 bf16x8 __attribute__((ext_vector_type(8)));
typedef __bf16 bf16x4 __attribute__((ext_vector_type(4)));
typedef float  f32x4  __attribute__((ext_vector_type(4)));

#define HT_STRIDE 520   // 512 + 8: +4-bank shift per f-row
#define WT_STRIDE 40    // 32 + 8 (k-panel width 32)

struct Smem {
    __bf16 hT[64][HT_STRIDE];       // h^T tile [f][j]   66,560 B
    __bf16 WT[64][WT_STRIDE];       // W panel [n][kl]    5,120 B
    float  ssrc[512], sdst[512];    //                    4,096 B
    float  rsum[256];               //                    1,024 B
    float  asrc[64], adst[64];      //                      512 B
};                                  // 77,312 B -> 2 blocks/CU (154.6 KB)

__device__ inline bf16x8 ld8(const float* p) {
    float4 a0 = *(const float4*)p;
    float4 a1 = *(const float4*)(p + 4);
    bf16x8 r;
    r[0]=(__bf16)a0.x; r[1]=(__bf16)a0.y; r[2]=(__bf16)a0.z; r[3]=(__bf16)a0.w;
    r[4]=(__bf16)a1.x; r[5]=(__bf16)a1.y; r[6]=(__bf16)a1.z; r[7]=(__bf16)a1.w;
    return r;
}

__global__ __launch_bounds__(512, 4) void k_gat(const float* __restrict__ x,
                                                const float* __restrict__ adj,
                                                const float* __restrict__ W,
                                                const float* __restrict__ a,
                                                float* __restrict__ out) {
    __shared__ Smem sm;
    const int ihalf = blockIdx.x, h = blockIdx.y, b = blockIdx.z;
    const int tid  = threadIdx.x;
    const int wave = tid >> 6, lane = tid & 63;
    const int quad = lane >> 4, col = lane & 15;

    // stage 0: a -> LDS (fp32)
    if (tid < 128) {
        float v = a[h * 128 + tid];
        if (tid < 64) sm.asrc[tid] = v; else sm.adst[tid - 64] = v;
    }

    // stage 1: h = x[b] @ W[:, h*64..h*64+64) -> hT[f][j], full 512 j.
    // K=256 in 8 panels of 32; W panel staged fp32->bf16 each iteration.
    {
        const float* xb = x + (long)b * 512 * 256;
        f32x4 acc[4][4] = {};
        const int c = tid & 63, kl = tid >> 6;       // 64 cols x 8 k-lanes
        for (int ks = 0; ks < 8; ++ks) {
            #pragma unroll
            for (int t = 0; t < 4; ++t)              // coalesced in c
                sm.WT[c][kl + t * 8] = (__bf16)W[(long)(ks * 32 + kl + t * 8) * 512 + h * 64 + c];
            __syncthreads();
            bf16x8 av[4], bv[4];
            #pragma unroll
            for (int it = 0; it < 4; ++it)           // A[m=col][k=quad*8+u]
                av[it] = ld8(xb + (long)(wave * 64 + it * 16 + col) * 256 + ks * 32 + quad * 8);
            #pragma unroll
            for (int nt = 0; nt < 4; ++nt)           // B[k][n=col]
                bv[nt] = *(const bf16x8*)(&sm.WT[nt * 16 + col][quad * 8]);
            #pragma unroll
            for (int it = 0; it < 4; ++it)
                #pragma unroll
                for (int nt = 0; nt < 4; ++nt)
                    acc[it][nt] = __builtin_amdgcn_mfma_f32_16x16x32_bf16(av[it], bv[nt], acc[it][nt], 0, 0, 0);
            __syncthreads();                         // frag reads done before re-stage
        }
        #pragma unroll
        for (int it = 0; it < 4; ++it)
            #pragma unroll
            for (int nt = 0; nt < 4; ++nt) {
                int f = nt * 16 + col;               // C/D: col=f, row=node
                int j = wave * 64 + it * 16 + quad * 4;
                bf16x4 pk = { (__bf16)acc[it][nt][0], (__bf16)acc[it][nt][1],
                              (__bf16)acc[it][nt][2], (__bf16)acc[it][nt][3] };
                *(bf16x4*)(&sm.hT[f][j]) = pk;
            }
    }
    __syncthreads();

    // stage 2: s_src[j], s_dst[j] = h_j . a  (all 512 j; fp32 accum)
    {
        float as = 0.f, ad = 0.f;
        #pragma unroll 8
        for (int f = 0; f < 64; ++f) {
            float v = (float)sm.hT[f][tid];
            as += v * sm.asrc[f];
            ad += v * sm.adst[f];
        }
        sm.ssrc[tid] = as;
        sm.sdst[tid] = ad;
    }
    __syncthreads();

    // stage 3: fused P-gen + P@h MFMA + row sums, for this block's 256 i.
    {
        float si[2], sacc[2] = {0.f, 0.f};
        const float* arow[2];
        #pragma unroll
        for (int it = 0; it < 2; ++it) {
            int i = ihalf * 256 + wave * 32 + it * 16 + col;   // A-row m=lane&15
            si[it]   = sm.ssrc[i & 511];
            arow[it] = adj + ((long)(b * 512 + i)) * 512;
        }
        f32x4 acc[2][4] = {};
        for (int ks = 0; ks < 16; ++ks) {            // K = 512 neighbors
            int j0 = ks * 32 + quad * 8;
            f32x4 s0 = *(const f32x4*)&sm.sdst[j0];
            f32x4 s1 = *(const f32x4*)&sm.sdst[j0 + 4];
            float sd[8] = {s0[0],s0[1],s0[2],s0[3],s1[0],s1[1],s1[2],s1[3]};
            bf16x8 P[2];
            #pragma unroll
            for (int it = 0; it < 2; ++it) {
                float4 a0 = *(const float4*)(arow[it] + j0);
                float4 a1 = *(const float4*)(arow[it] + j0 + 4);
                float am[8] = {a0.x,a0.y,a0.z,a0.w,a1.x,a1.y,a1.z,a1.w};
                #pragma unroll
                for (int u = 0; u < 8; ++u) {
                    float e = si[it] + sd[u];
                    e = e > 0.f ? e : ALPHA * e;
                    float p = (am[u] > 0.f) ? __expf(e) : 0.f;   // unnormalized
                    __bf16 pb = (__bf16)p;
                    sacc[it] += (float)pb;           // sum the rounded p
                    P[it][u] = pb;
                }
            }
            #pragma unroll
            for (int nt = 0; nt < 4; ++nt) {
                bf16x8 bv = *(const bf16x8*)(&sm.hT[nt * 16 + col][j0]);
                #pragma unroll
                for (int it = 0; it < 2; ++it)
                    acc[it][nt] = __builtin_amdgcn_mfma_f32_16x16x32_bf16(P[it], bv, acc[it][nt], 0, 0, 0);
            }
        }
        // fold per-quad partial row sums (same i lives in all 4 quads)
        #pragma unroll
        for (int it = 0; it < 2; ++it) {
            float s = sacc[it];
            s += __shfl_xor(s, 16);
            s += __shfl_xor(s, 32);
            if (quad == 0) sm.rsum[wave * 32 + it * 16 + col] = s;
        }
        __syncthreads();
        // epilogue: normalize, store fp32
        #pragma unroll
        for (int it = 0; it < 2; ++it)
            #pragma unroll
            for (int r = 0; r < 4; ++r) {
                int li = wave * 32 + it * 16 + quad * 4 + r;   // C/D row (local)
                int i  = ihalf * 256 + li;
                float s = sm.rsum[li];
                float inv = (s > 0.f) ? 1.0f / s : 0.f;
                float* orow = out + ((long)(b * 512 + i)) * 512 + h * 64;
                #pragma unroll
                for (int nt = 0; nt < 4; ++nt)
                    orow[nt * 16 + col] = acc[it][nt][r] * inv;
            }
    }
}

// ---- launch ---------------------------------------------------------------
extern "C" void kernel_launch(void* const* d_in, const int* in_sizes, int n_in,
                              void* d_out, int out_size, void* d_ws, size_t ws_size,
                              hipStream_t stream) {
    const float* x   = (const float*)d_in[0];   // (32,512,256)
    const float* adj = (const float*)d_in[1];   // (32,512,512), {0,1}
    const float* W   = (const float*)d_in[2];   // (256,512)
    const float* a   = (const float*)d_in[3];   // (8,128)
    float* out = (float*)d_out;                 // (32,512,512)
    (void)d_ws; (void)ws_size;

    k_gat<<<dim3(2, 8, 32), 512, 0, stream>>>(x, adj, W, a, out);
}